// Round 5
// baseline (621.098 us; speedup 1.0000x reference)
//
#include <hip/hip_runtime.h>

#define B_ 4096
#define T_ 512
#define F_ 8
#define H_ 16

typedef __fp16 f16;
typedef __fp16 f16x2 __attribute__((ext_vector_type(2)));
typedef __fp16 f16x8 __attribute__((ext_vector_type(8)));
typedef float f32x4 __attribute__((ext_vector_type(4)));

#define LOG2E 1.442695041f
#define N2LOG2E (-2.885390082f)

__device__ __forceinline__ float sigf(float x) {
    return __builtin_amdgcn_rcpf(1.0f + __builtin_amdgcn_exp2f(-LOG2E * x));
}
__device__ __forceinline__ float tanh_f(float x) {
    return __builtin_fmaf(2.0f,
        __builtin_amdgcn_rcpf(1.0f + __builtin_amdgcn_exp2f(N2LOG2E * x)), -1.0f);
}
__device__ __forceinline__ f32x4 mfma32(f16x8 a, f16x8 b, f32x4 c) {
    return __builtin_amdgcn_mfma_f32_16x16x32_f16(a, b, c, 0, 0, 0);
}
__device__ __forceinline__ float bperm(int ba, float v) {
    return __builtin_bit_cast(float,
        __builtin_amdgcn_ds_bpermute(ba, __builtin_bit_cast(int, v)));
}
__device__ __forceinline__ f16x8 pack8(f32x4 a, f32x4 b) {
    f16x2 p0 = __builtin_amdgcn_cvt_pkrtz(a[0], a[1]);
    f16x2 p1 = __builtin_amdgcn_cvt_pkrtz(a[2], a[3]);
    f16x2 p2 = __builtin_amdgcn_cvt_pkrtz(b[0], b[1]);
    f16x2 p3 = __builtin_amdgcn_cvt_pkrtz(b[2], b[3]);
    f16x8 r;
    r[0] = p0[0]; r[1] = p0[1]; r[2] = p1[0]; r[3] = p1[1];
    r[4] = p2[0]; r[5] = p2[1]; r[6] = p3[0]; r[7] = p3[1];
    return r;
}
// 8 f32 -> f16 hi + f16 residual lo (w ~= hi+lo to ~2^-22 rel)
__device__ __forceinline__ void split8(f32x4 a, f32x4 b, f16x8& hi, f16x8& lo) {
    hi = pack8(a, b);
    f32x4 ra, rb;
    ra[0] = a[0] - (float)hi[0]; ra[1] = a[1] - (float)hi[1];
    ra[2] = a[2] - (float)hi[2]; ra[3] = a[3] - (float)hi[3];
    rb[0] = b[0] - (float)hi[4]; rb[1] = b[1] - (float)hi[5];
    rb[2] = b[2] - (float)hi[6]; rb[3] = b[3] - (float)hi[7];
    lo = pack8(ra, rb);
}

// MFMA K=32 LSTM autoencoder, bpermute-packed activations.
// One wave = 4 chains (MFMA cols 0..3). 256 blocks x 4 waves = 1024 waves = 1/SIMD.
// Roles of lane l (q=l>>4, n=l&15):
//   MFMA A-role: row m = 16*blk + n, k = 8q+j.
//   MFMA B/D-role: col (chain) = n, B k = 8q+j, D rows 4q+e.
//   Activation role: chain = q, unit = n (all 64 lanes valid -> 4x fewer trans).
// Gather: lane (q,n) pulls acc[blk][n&3] from source lane 16*(n>>2)+q (16 bperm
// + 12 sel). Scatter: B-lane (q,n) pulls h units (q&1)*8+j of chain n from lane
// 16n+(q&1)*8+j (8 bperm). K=32 packs hi/lo precision terms into K halves.
__global__ __launch_bounds__(256, 1) void lstm_ae_kernel(
    const float* __restrict__ x,
    const float* __restrict__ eWih, const float* __restrict__ eWhh,
    const float* __restrict__ ebih, const float* __restrict__ ebhh,
    const float* __restrict__ dWih, const float* __restrict__ dWhh,
    const float* __restrict__ dbih, const float* __restrict__ dbhh,
    const float* __restrict__ oW,   const float* __restrict__ ob,
    float* __restrict__ out)
{
    const int l  = threadIdx.x & 63;
    const int wv = threadIdx.x >> 6;
    const int q  = l >> 4;
    const int n  = l & 15;
    const int b0 = (blockIdx.x * 4 + wv) * 4;
    const f16x8 z8 = {};
    const f32x4 z4 = {};

    const int gaddr = ((((n >> 2) << 4) | q) << 2);       // gather src lane*4
    int saddr[8];
#pragma unroll
    for (int j = 0; j < 8; ++j)
        saddr[j] = (((n << 4) + (q & 1) * 8 + j) & 63) << 2;
    const bool em0 = (l & 3) == 0, em1 = (l & 3) == 1, em2 = (l & 3) == 2;
    const bool qlt2 = (q < 2), qe0 = (q == 0), qe1 = (q == 1);

    // ---------------- encoder A-fragments ----------------
    // A1 = [Wih_hi | Wih_lo | Whh_hi(0-7) | Whh_hi(8-15)]  (x_hi, h_hi terms)
    // A2 = [Wih_hi | 0      | Whh_lo(0-7) | Whh_lo(8-15)]  (x_lo, h_hi terms)
    // A3 = [0      | 0      | Whh_hi(0-7) | Whh_hi(8-15)]  (h_lo term)
    f16x8 eA1[4], eA2[4], eA3[4];
    f32x4 biasE[4];
#pragma unroll
    for (int blk = 0; blk < 4; ++blk) {
        const int m = blk * 16 + n;
        const float* pa = qlt2 ? (eWih + m * 8) : (eWhh + m * 16 + (q & 1) * 8);
        f32x4 wa = *(const f32x4*)pa;
        f32x4 wb = *(const f32x4*)(pa + 4);
        f16x8 hi, lo; split8(wa, wb, hi, lo);
        eA1[blk] = qe1 ? lo : hi;
        eA2[blk] = qe0 ? hi : (qlt2 ? z8 : lo);
        eA3[blk] = qlt2 ? z8 : hi;
        f32x4 b1 = *(const f32x4*)(ebih + blk * 16 + 4 * q);
        f32x4 b2 = *(const f32x4*)(ebhh + blk * 16 + 4 * q);
        biasE[blk] = b1 + b2;
    }

    float cst = 0.0f;
    f16x8 hip = z8, lop = z8;

    // x ring buffer (prefetch depth 3)
    const bool ld = (n < 4) && qlt2;
    const float* xb = x + (size_t)(b0 + n) * (T_ * F_);
    f32x4 xa[4] = {}, xc[4] = {};
    if (ld) {
#pragma unroll
        for (int u = 0; u < 3; ++u) {
            xa[u] = *(const f32x4*)(xb + u * F_);
            xc[u] = *(const f32x4*)(xb + u * F_ + 4);
        }
    }

    // ---------------- encoder ----------------
    for (int t = 0; t < T_; t += 4) {
#pragma unroll
        for (int u = 0; u < 4; ++u) {
            const int tt = t + u;
            f32x4 xv0 = xa[u], xv1 = xc[u];
            if (ld && tt + 3 < T_) {
                xa[(u + 3) & 3] = *(const f32x4*)(xb + (tt + 3) * F_);
                xc[(u + 3) & 3] = *(const f32x4*)(xb + (tt + 3) * F_ + 4);
            }
            f16x8 xhi, xlo; split8(xv0, xv1, xhi, xlo);
            f16x8 B1 = qlt2 ? xhi : hip;
            f16x8 B2 = qe0  ? xlo : hip;

            f32x4 a0 = mfma32(eA1[0], B1, biasE[0]);
            f32x4 a1 = mfma32(eA1[1], B1, biasE[1]);
            f32x4 a2 = mfma32(eA1[2], B1, biasE[2]);
            f32x4 a3 = mfma32(eA1[3], B1, biasE[3]);
            a0 = mfma32(eA2[0], B2, a0);
            a1 = mfma32(eA2[1], B2, a1);
            a2 = mfma32(eA2[2], B2, a2);
            a3 = mfma32(eA2[3], B2, a3);
            a0 = mfma32(eA3[0], lop, a0);
            a1 = mfma32(eA3[1], lop, a1);
            a2 = mfma32(eA3[2], lop, a2);
            a3 = mfma32(eA3[3], lop, a3);

            // gather pre-activations to packed (chain=q, unit=n) layout
            float t0, t1, t2, t3, gv0, gv1, gv2, gv3;
            t0 = bperm(gaddr, a0[0]); t1 = bperm(gaddr, a0[1]);
            t2 = bperm(gaddr, a0[2]); t3 = bperm(gaddr, a0[3]);
            gv0 = em0 ? t0 : em1 ? t1 : em2 ? t2 : t3;
            t0 = bperm(gaddr, a1[0]); t1 = bperm(gaddr, a1[1]);
            t2 = bperm(gaddr, a1[2]); t3 = bperm(gaddr, a1[3]);
            gv1 = em0 ? t0 : em1 ? t1 : em2 ? t2 : t3;
            t0 = bperm(gaddr, a2[0]); t1 = bperm(gaddr, a2[1]);
            t2 = bperm(gaddr, a2[2]); t3 = bperm(gaddr, a2[3]);
            gv2 = em0 ? t0 : em1 ? t1 : em2 ? t2 : t3;
            t0 = bperm(gaddr, a3[0]); t1 = bperm(gaddr, a3[1]);
            t2 = bperm(gaddr, a3[2]); t3 = bperm(gaddr, a3[3]);
            gv3 = em0 ? t0 : em1 ? t1 : em2 ? t2 : t3;

            const float gi = sigf(gv0), gf = sigf(gv1);
            const float gg = tanh_f(gv2), go = sigf(gv3);
            cst = __builtin_fmaf(gf, cst, gi * gg);
            const float hv = go * tanh_f(cst);

            // scatter h back to B-fragment layout
            f32x4 ha, hb;
            ha[0] = bperm(saddr[0], hv); ha[1] = bperm(saddr[1], hv);
            ha[2] = bperm(saddr[2], hv); ha[3] = bperm(saddr[3], hv);
            hb[0] = bperm(saddr[4], hv); hb[1] = bperm(saddr[5], hv);
            hb[2] = bperm(saddr[6], hv); hb[3] = bperm(saddr[7], hv);
            split8(ha, hb, hip, lop);
        }
    }

    // ------------- decoder fragments + constant input projection -----------
    f16x8 dA1[4], dA2[4], oA1, oA2;
    f32x4 xpC[4], obC = z4;
#pragma unroll
    for (int blk = 0; blk < 4; ++blk) {
        const int m = blk * 16 + n;
        const float* pi = dWih + m * 16 + (q & 1) * 8;
        f32x4 wa = *(const f32x4*)pi, wb = *(const f32x4*)(pi + 4);
        f16x8 hi, lo; split8(wa, wb, hi, lo);
        f16x8 xA1 = qlt2 ? hi : lo;
        f16x8 xA2 = qlt2 ? hi : z8;
        f32x4 bb = *(const f32x4*)(dbih + blk * 16 + 4 * q);
        f32x4 b2 = *(const f32x4*)(dbhh + blk * 16 + 4 * q);
        f32x4 p = mfma32(xA1, hip, bb + b2);     // dWih·hT + bias
        xpC[blk] = mfma32(xA2, lop, p);
        const float* ph = dWhh + m * 16 + (q & 1) * 8;
        f32x4 ya = *(const f32x4*)ph, yb = *(const f32x4*)(ph + 4);
        split8(ya, yb, hi, lo);
        dA1[blk] = qlt2 ? hi : lo;               // [Whh_hi | Whh_lo]
        dA2[blk] = qlt2 ? hi : z8;               // [Whh_hi | 0]
    }
    {
        f32x4 wa = z4, wb = z4;
        if (n < 8) {
            const float* po = oW + n * 16 + (q & 1) * 8;
            wa = *(const f32x4*)po; wb = *(const f32x4*)(po + 4);
        }
        f16x8 hi, lo; split8(wa, wb, hi, lo);
        oA1 = qlt2 ? hi : lo;
        oA2 = qlt2 ? hi : z8;
        if (qlt2) obC = *(const f32x4*)(ob + 4 * q);
    }

    cst = 0.0f; hip = z8; lop = z8;
    const size_t obase = (size_t)(b0 + n) * (T_ * F_) + 4 * q;
    const bool stv = (n < 4) && qlt2;

    // ---------------- decoder + fused output projection ----------------
#pragma unroll 2
    for (int t = 0; t < T_; ++t) {
        f32x4 a0 = mfma32(dA1[0], hip, xpC[0]);
        f32x4 a1 = mfma32(dA1[1], hip, xpC[1]);
        f32x4 a2 = mfma32(dA1[2], hip, xpC[2]);
        f32x4 a3 = mfma32(dA1[3], hip, xpC[3]);
        a0 = mfma32(dA2[0], lop, a0);
        a1 = mfma32(dA2[1], lop, a1);
        a2 = mfma32(dA2[2], lop, a2);
        a3 = mfma32(dA2[3], lop, a3);

        float t0, t1, t2, t3, gv0, gv1, gv2, gv3;
        t0 = bperm(gaddr, a0[0]); t1 = bperm(gaddr, a0[1]);
        t2 = bperm(gaddr, a0[2]); t3 = bperm(gaddr, a0[3]);
        gv0 = em0 ? t0 : em1 ? t1 : em2 ? t2 : t3;
        t0 = bperm(gaddr, a1[0]); t1 = bperm(gaddr, a1[1]);
        t2 = bperm(gaddr, a1[2]); t3 = bperm(gaddr, a1[3]);
        gv1 = em0 ? t0 : em1 ? t1 : em2 ? t2 : t3;
        t0 = bperm(gaddr, a2[0]); t1 = bperm(gaddr, a2[1]);
        t2 = bperm(gaddr, a2[2]); t3 = bperm(gaddr, a2[3]);
        gv2 = em0 ? t0 : em1 ? t1 : em2 ? t2 : t3;
        t0 = bperm(gaddr, a3[0]); t1 = bperm(gaddr, a3[1]);
        t2 = bperm(gaddr, a3[2]); t3 = bperm(gaddr, a3[3]);
        gv3 = em0 ? t0 : em1 ? t1 : em2 ? t2 : t3;

        const float gi = sigf(gv0), gf = sigf(gv1);
        const float gg = tanh_f(gv2), go = sigf(gv3);
        cst = __builtin_fmaf(gf, cst, gi * gg);
        const float hv = go * tanh_f(cst);

        f32x4 ha, hb;
        ha[0] = bperm(saddr[0], hv); ha[1] = bperm(saddr[1], hv);
        ha[2] = bperm(saddr[2], hv); ha[3] = bperm(saddr[3], hv);
        hb[0] = bperm(saddr[4], hv); hb[1] = bperm(saddr[5], hv);
        hb[2] = bperm(saddr[6], hv); hb[3] = bperm(saddr[7], hv);
        split8(ha, hb, hip, lop);

        f32x4 o1 = mfma32(oA1, hip, obC);        // oW·h + ob
        o1 = mfma32(oA2, lop, o1);
        if (stv) *(f32x4*)(out + obase + (size_t)t * F_) = o1;
    }
}

extern "C" void kernel_launch(void* const* d_in, const int* in_sizes, int n_in,
                              void* d_out, int out_size, void* d_ws, size_t ws_size,
                              hipStream_t stream) {
    (void)in_sizes; (void)n_in; (void)d_ws; (void)ws_size; (void)out_size;
    lstm_ae_kernel<<<dim3(B_ / 16), dim3(256), 0, stream>>>(
        (const float*)d_in[0],
        (const float*)d_in[1], (const float*)d_in[2],
        (const float*)d_in[3], (const float*)d_in[4],
        (const float*)d_in[5], (const float*)d_in[6],
        (const float*)d_in[7], (const float*)d_in[8],
        (const float*)d_in[9], (const float*)d_in[10],
        (float*)d_out);
}

// Round 6
// 353.888 us; speedup vs baseline: 1.7551x; 1.7551x over previous
//
#include <hip/hip_runtime.h>

#define B_ 4096
#define T_ 512
#define F_ 8
#define H_ 16

typedef float f32x2 __attribute__((ext_vector_type(2)));
typedef float f32x4v __attribute__((ext_vector_type(4)));

__device__ __forceinline__ f32x2 pkfma(f32x2 a, f32x2 b, f32x2 c) {
    return __builtin_elementwise_fma(a, b, c);
}
#define SV2(v, a, b) __builtin_shufflevector(v, v, a, b)

#define LOG2E 1.442695041f
#define N2LOG2E (-2.885390082f)

__device__ __forceinline__ float sigf(float x) {
    return __builtin_amdgcn_rcpf(1.0f + __builtin_amdgcn_exp2f(-LOG2E * x));
}
__device__ __forceinline__ float tanh_f(float x) {
    return __builtin_fmaf(2.0f,
        __builtin_amdgcn_rcpf(1.0f + __builtin_amdgcn_exp2f(N2LOG2E * x)), -1.0f);
}

// 4 chains per wave, gate-quad locality.
// Lane l: chain cw=l>>4, unit u=l&15, owns gate rows {u,u+16,u+32,u+48}
// (i,f,g,o of unit u). After the matvec all 4 gates of the lane's unit are
// lane-local: zero cross-lane gate exchange, every transcendental computed
// exactly once (4 chain-steps per wave-step over 64 units = 64 lanes).
// h broadcast per chain via LDS (write 16 scalars, read 4x b128, padded
// strides -> no bank conflicts). 4096/4 = 1024 waves = 1 wave/SIMD; each
// gate's accumulator chain starts with the x-part (independent of h) so the
// LDS h roundtrip hides under issue.
__global__ __launch_bounds__(256, 1) void lstm_ae_kernel(
    const float* __restrict__ x,
    const float* __restrict__ eWih, const float* __restrict__ eWhh,
    const float* __restrict__ ebih, const float* __restrict__ ebhh,
    const float* __restrict__ dWih, const float* __restrict__ dWhh,
    const float* __restrict__ dbih, const float* __restrict__ dbhh,
    const float* __restrict__ oW,   const float* __restrict__ ob,
    float* __restrict__ out)
{
    const int tid = threadIdx.x;
    const int wv  = tid >> 6;        // wave in block
    const int l   = tid & 63;
    const int cw  = l >> 4;          // chain within wave, 0..3
    const int u   = l & 15;          // hidden unit
    const int bw  = blockIdx.x * 16 + wv * 4;   // wave's first chain
    const int b   = bw + cw;

    // padded strides: h group stride 10 f32x2 (80B, 16B-aligned, distinct
    // banks per cw); x chain stride 33 steps (1056B) -> bank offset 8.
    __shared__ __align__(16) f32x2 hsh[4][40];
    __shared__ __align__(16) f32x2 xsh[4][4][33][4];

    const f32x2 zero2 = {0.0f, 0.0f};

    // ---------------- encoder weights ----------------
    f32x2 wh[4][8], wi[4][4];
    float bias[4];
#pragma unroll
    for (int g = 0; g < 4; ++g) {
        const int r = g * 16 + u;
        const f32x2* phh = (const f32x2*)(eWhh + r * 16);
#pragma unroll
        for (int p = 0; p < 8; ++p) wh[g][p] = phh[p];
        const f32x2* pih = (const f32x2*)(eWih + r * 8);
#pragma unroll
        for (int p = 0; p < 4; ++p) wi[g][p] = pih[p];
        bias[g] = ebih[r] + ebhh[r];
    }

    float c = 0.0f;
    f32x2 hb[8];
#pragma unroll
    for (int p = 0; p < 8; ++p) hb[p] = zero2;

    float* hp = (float*)&hsh[wv][cw * 10];

    // x chunk prefetch: iter i covers chain bw+i, step c0+(l>>1), half l&1
    const int ps = l >> 1, phx = l & 1;
    f32x4v xr[4];
#pragma unroll
    for (int i = 0; i < 4; ++i)
        xr[i] = *(const f32x4v*)(x + ((size_t)(bw + i) * T_ + ps) * F_ + phx * 4);

    // ---------------- encoder ----------------
    for (int c0 = 0; c0 < T_; c0 += 32) {
        __builtin_amdgcn_wave_barrier();
#pragma unroll
        for (int i = 0; i < 4; ++i)
            *(f32x4v*)&xsh[wv][i][ps][phx * 2] = xr[i];
        __builtin_amdgcn_wave_barrier();
        if (c0 + 32 < T_) {
#pragma unroll
            for (int i = 0; i < 4; ++i)
                xr[i] = *(const f32x4v*)(
                    x + ((size_t)(bw + i) * T_ + (c0 + 32 + ps)) * F_ + phx * 4);
        }
        for (int s = 0; s < 32; ++s) {
            f32x4v xq0 = *(const f32x4v*)&xsh[wv][cw][s][0];
            f32x4v xq1 = *(const f32x4v*)&xsh[wv][cw][s][2];
            f32x2 x0 = SV2(xq0, 0, 1), x1 = SV2(xq0, 2, 3);
            f32x2 x2 = SV2(xq1, 0, 1), x3 = SV2(xq1, 2, 3);

            f32x2 acc[4];
#pragma unroll
            for (int g = 0; g < 4; ++g) {      // x-part first (h-independent)
                f32x2 a = pkfma(wi[g][0], x0, f32x2{bias[g], 0.0f});
                a = pkfma(wi[g][1], x1, a);
                a = pkfma(wi[g][2], x2, a);
                a = pkfma(wi[g][3], x3, a);
#pragma unroll
                for (int p = 0; p < 8; ++p) a = pkfma(wh[g][p], hb[p], a);
                acc[g] = a;
            }
            const float gi = sigf(acc[0].x + acc[0].y);
            const float gf = sigf(acc[1].x + acc[1].y);
            const float gg = tanh_f(acc[2].x + acc[2].y);
            const float go = sigf(acc[3].x + acc[3].y);
            c = __builtin_fmaf(gf, c, gi * gg);
            const float ht = go * tanh_f(c);

            __builtin_amdgcn_wave_barrier();
            hp[u] = ht;
            __builtin_amdgcn_wave_barrier();
            f32x4v h0 = *(const f32x4v*)&hp[0];
            f32x4v h1 = *(const f32x4v*)&hp[4];
            f32x4v h2 = *(const f32x4v*)&hp[8];
            f32x4v h3 = *(const f32x4v*)&hp[12];
            hb[0] = SV2(h0, 0, 1); hb[1] = SV2(h0, 2, 3);
            hb[2] = SV2(h1, 0, 1); hb[3] = SV2(h1, 2, 3);
            hb[4] = SV2(h2, 0, 1); hb[5] = SV2(h2, 2, 3);
            hb[6] = SV2(h3, 0, 1); hb[7] = SV2(h3, 2, 3);
        }
    }

    // ---------- decoder weights + constant input projection ----------
    f32x2 wd[4][8];
    float xp[4];
#pragma unroll
    for (int g = 0; g < 4; ++g) {
        const int r = g * 16 + u;
        const f32x2* pih = (const f32x2*)(dWih + r * 16);
        f32x2 a = zero2;
#pragma unroll
        for (int p = 0; p < 8; ++p) a = pkfma(pih[p], hb[p], a);
        xp[g] = dbih[r] + dbhh[r] + a.x + a.y;
        const f32x2* phh = (const f32x2*)(dWhh + r * 16);
#pragma unroll
        for (int p = 0; p < 8; ++p) wd[g][p] = phh[p];
    }
    f32x2 wo[8];
    {
        const f32x2* po = (const f32x2*)(oW + (u & 7) * 16);
#pragma unroll
        for (int p = 0; p < 8; ++p) wo[p] = po[p];
    }
    const float obv = ob[u & 7];
    const bool st = (u < 8);
    float* outp = out + (size_t)b * (T_ * F_);

    c = 0.0f;
#pragma unroll
    for (int p = 0; p < 8; ++p) hb[p] = zero2;

    // ---------------- decoder + fused output projection ----------------
    for (int t = 0; t < T_; ++t) {
        f32x2 acc[4];
#pragma unroll
        for (int g = 0; g < 4; ++g) {
            f32x2 a = pkfma(wd[g][0], hb[0], f32x2{xp[g], 0.0f});
#pragma unroll
            for (int p = 1; p < 8; ++p) a = pkfma(wd[g][p], hb[p], a);
            acc[g] = a;
        }
        const float gi = sigf(acc[0].x + acc[0].y);
        const float gf = sigf(acc[1].x + acc[1].y);
        const float gg = tanh_f(acc[2].x + acc[2].y);
        const float go = sigf(acc[3].x + acc[3].y);
        c = __builtin_fmaf(gf, c, gi * gg);
        const float ht = go * tanh_f(c);

        __builtin_amdgcn_wave_barrier();
        hp[u] = ht;
        __builtin_amdgcn_wave_barrier();
        f32x4v h0 = *(const f32x4v*)&hp[0];
        f32x4v h1 = *(const f32x4v*)&hp[4];
        f32x4v h2 = *(const f32x4v*)&hp[8];
        f32x4v h3 = *(const f32x4v*)&hp[12];
        hb[0] = SV2(h0, 0, 1); hb[1] = SV2(h0, 2, 3);
        hb[2] = SV2(h1, 0, 1); hb[3] = SV2(h1, 2, 3);
        hb[4] = SV2(h2, 0, 1); hb[5] = SV2(h2, 2, 3);
        hb[6] = SV2(h3, 0, 1); hb[7] = SV2(h3, 2, 3);

        // output projection (feature u&7, 2x redundant across the group)
        f32x2 oa = pkfma(wo[0], hb[0], f32x2{obv, 0.0f});
#pragma unroll
        for (int p = 1; p < 8; ++p) oa = pkfma(wo[p], hb[p], oa);
        if (st) outp[t * F_ + u] = oa.x + oa.y;
    }
}

extern "C" void kernel_launch(void* const* d_in, const int* in_sizes, int n_in,
                              void* d_out, int out_size, void* d_ws, size_t ws_size,
                              hipStream_t stream) {
    (void)in_sizes; (void)n_in; (void)d_ws; (void)ws_size; (void)out_size;
    lstm_ae_kernel<<<dim3(B_ / 16), dim3(256), 0, stream>>>(
        (const float*)d_in[0],
        (const float*)d_in[1], (const float*)d_in[2],
        (const float*)d_in[3], (const float*)d_in[4],
        (const float*)d_in[5], (const float*)d_in[6],
        (const float*)d_in[7], (const float*)d_in[8],
        (const float*)d_in[9], (const float*)d_in[10],
        (float*)d_out);
}